// Round 1
// baseline (409.415 us; speedup 1.0000x reference)
//
#include <hip/hip_runtime.h>
#include <stdint.h>

// Problem constants (B=2, NV=25000, C=32, NR=3, ND=16, F=64)
#define NVERT 25000      // vertices per batch
#define NPAIR 25000      // total vertex-pairs (B*NV/2)

typedef __bf16  bf16x8 __attribute__((ext_vector_type(8)));
typedef float   f32x16 __attribute__((ext_vector_type(16)));

#define NCHUNK 98                       // 96 conv chunks (r,ch,j) + 2 center chunks
#define BPACK_HALF_USHORT (NCHUNK*512)  // ushorts per f-half fragment pack
#define LDS_B   (NCHUNK*1024)           // 100352 B of B-fragments in LDS
#define ROWB    80                      // patch row stride bytes (32 bf16 + pad; 20 dwords -> 2-way banks max)
#define VSTRIDE (49*ROWB)               // per-vertex patch (48 rows + 1 center row) = 3920
#define PSTRIDE (2*VSTRIDE)             // per vertex-pair = 7840
#define WSTRIDE (2*PSTRIDE)             // per wave (2 pairs) = 15680
#define LDS_TOT (LDS_B + 4*WSTRIDE)     // 163072 <= 163840 (160 KiB)

__device__ __forceinline__ unsigned short f2bf(float f) {
  unsigned int u = __float_as_uint(f);
  u += 0x7FFFu + ((u >> 16) & 1u);   // round-to-nearest-even
  return (unsigned short)(u >> 16);
}

// lane-rotate within 16-lane rows: dst[i] = src[(i+1)&15]  (row_ror:15)
__device__ __forceinline__ bf16x8 rot16(bf16x8 x) {
  union { bf16x8 v; int i[4]; } u;
  u.v = x;
#pragma unroll
  for (int k = 0; k < 4; ++k)
    u.i[k] = __builtin_amdgcn_update_dpp(0, u.i[k], 0x12F, 0xF, 0xF, true);
  return u.v;
}

// Pack kernel (3,16,32,64) + center_kernel (32,64) into MFMA B-fragment order, bf16.
// Layout: bpack[fh(2)][kc(98)][lane(64)][i(8)] ushort.
// kc = (r*2+ch)*16 + j for conv; kc = 96+ch for center. B[k][n]: n=lane&31, k=8*(lane>>5)+i, c=ch*16+k.
__global__ __launch_bounds__(256) void prepack_kernel(
    const float* __restrict__ kern, const float* __restrict__ ckern,
    unsigned short* __restrict__ bpack)
{
  int tid = blockIdx.x*256 + threadIdx.x;
  if (tid >= 2*BPACK_HALF_USHORT) return;
  int fh  = tid / BPACK_HALF_USHORT;
  int rem = tid - fh*BPACK_HALF_USHORT;
  int kc  = rem >> 9;
  int e   = rem & 511;
  int l   = e >> 3, i = e & 7;
  int f   = fh*32 + (l & 31);
  int kk  = ((l >> 5) << 3) + i;
  float v;
  if (kc < 96) {
    int r = kc >> 5, ch = (kc >> 4) & 1, j = kc & 15;
    int c = ch*16 + kk;
    v = kern[((r*16 + j)*32 + c)*64 + f];
  } else {
    int c = (kc - 96)*16 + kk;
    v = ckern[c*64 + f];
  }
  bpack[tid] = f2bf(v);
}

__global__ __launch_bounds__(256, 1) void conv_kernel(
    const float* __restrict__ y,
    const int*   __restrict__ em,     // exp_map int pairs (b,v), flat (u*48 + r*16+dd)
    const float* __restrict__ bias,
    const unsigned short* __restrict__ bpack,
    float* __restrict__ out)
{
  extern __shared__ __align__(16) char smem[];
  const int fh  = blockIdx.x & 1;     // which 32-wide f half
  const int bl  = blockIdx.x >> 1;    // 0..127
  const int tid = threadIdx.x;
  const int w   = tid >> 6;           // wave 0..3
  const int l   = tid & 63;

  // ---- stage this f-half's B fragments into LDS (once per block) ----
  {
    const uint4* src = (const uint4*)(bpack + (size_t)fh * BPACK_HALF_USHORT);
    uint4* dst = (uint4*)smem;
    for (int idx = tid; idx < LDS_B/16; idx += 256) dst[idx] = src[idx];
  }
  __syncthreads();
  // After this point waves are fully independent (per-wave patch regions, per-wave DS ordering).

  char* pbase = smem + LDS_B + w * WSTRIDE;
  const float biasv = bias[fh*32 + (l & 31)];
  const int gw = bl*4 + w;            // global wave id within f-half, 0..511
  const int q  = (l >> 4) & 1;        // A-operand: which vertex of the pair (m>>4)
  const int d  = l & 15;              // A-operand: direction (m&15)
  const int hi = l >> 5;              // A/B operand: k-half selector
  const char* bbase = smem + (size_t)l * 16;

  for (int t = 0; t < 25; ++t) {
    const int vp0 = (t*512 + gw)*2;
    const int vp1 = vp0 + 1;
    if (vp0 >= NPAIR) break;

    // ---- stage patches (2 vertex-pairs = 4 vertices) into this wave's LDS region ----
#pragma unroll
    for (int p = 0; p < 2; ++p) {
      const int vp = vp0 + p;
      if (vp >= NPAIR) break;
      char* sb = pbase + p*PSTRIDE;
      const int u0 = vp*2;
      for (int it = 0; it < 12; ++it) {            // 8 rows per pass, lanes: (row=l>>3, c-quarter=l&7)
        const int qq = it & 1;
        const int u  = u0 + qq;
        const int rowRel = (it >> 1)*8 + (l >> 3); // 0..47 = r*16+dd, matches exp_map flattening
        const int cp = l & 7;
        const int2 e = ((const int2*)em)[u*48 + rowRel];
        const float4 yv = *(const float4*)(y + ((size_t)e.x*NVERT + (size_t)e.y)*32 + cp*4);
        uint2 pk;
        pk.x = (unsigned)f2bf(yv.x) | ((unsigned)f2bf(yv.y) << 16);
        pk.y = (unsigned)f2bf(yv.z) | ((unsigned)f2bf(yv.w) << 16);
        *(uint2*)(sb + qq*VSTRIDE + rowRel*ROWB + cp*8) = pk;
      }
      if (l < 16) {                                 // center rows (row 48): y[u] itself
        const int qq = (l >> 3) & 1;
        const int u  = u0 + qq;
        const int cp = l & 7;
        const float4 yv = *(const float4*)(y + (size_t)u*32 + cp*4);
        uint2 pk;
        pk.x = (unsigned)f2bf(yv.x) | ((unsigned)f2bf(yv.y) << 16);
        pk.y = (unsigned)f2bf(yv.z) | ((unsigned)f2bf(yv.w) << 16);
        *(uint2*)(sb + qq*VSTRIDE + 48*ROWB + cp*8) = pk;
      }
    }

    // ---- compute: 98 MFMAs per vertex-pair, B-fragment shared across both pairs ----
    f32x16 acc0, acc1;
#pragma unroll
    for (int k = 0; k < 16; ++k) { acc0[k] = 0.f; acc1[k] = 0.f; }

    const int abase = q*VSTRIDE + d*ROWB + hi*16;
#pragma unroll
    for (int r = 0; r < 3; ++r) {
#pragma unroll
      for (int ch = 0; ch < 2; ++ch) {
        const char* ap = pbase + abase + r*(16*ROWB) + ch*32;
        bf16x8 a0 = *(const bf16x8*)ap;             // rows t=d at j=0; rotated in-register for j>0
        bf16x8 a1 = *(const bf16x8*)(ap + PSTRIDE);
        const char* bp = bbase + (size_t)((r*2 + ch)*16) * 1024;
#pragma unroll
        for (int j = 0; j < 16; ++j) {
          const bf16x8 b = *(const bf16x8*)(bp + j*1024);
          acc0 = __builtin_amdgcn_mfma_f32_32x32x16_bf16(a0, b, acc0, 0, 0, 0);
          acc1 = __builtin_amdgcn_mfma_f32_32x32x16_bf16(a1, b, acc1, 0, 0, 0);
          if (j < 15) { a0 = rot16(a0); a1 = rot16(a1); }
        }
      }
    }
    // center term: A-rows identical per vertex (broadcast LDS read), 2 chunks
#pragma unroll
    for (int ch = 0; ch < 2; ++ch) {
      const char* ap = pbase + q*VSTRIDE + 48*ROWB + ch*32 + hi*16;
      bf16x8 a0 = *(const bf16x8*)ap;
      bf16x8 a1 = *(const bf16x8*)(ap + PSTRIDE);
      const bf16x8 b = *(const bf16x8*)(bbase + (size_t)(96 + ch)*1024);
      acc0 = __builtin_amdgcn_mfma_f32_32x32x16_bf16(a0, b, acc0, 0, 0, 0);
      acc1 = __builtin_amdgcn_mfma_f32_32x32x16_bf16(a1, b, acc1, 0, 0, 0);
    }

    // ---- epilogue: max over d, +bias, relu, store ----
    // C/D layout (m74/m101): n = lane&31, m = (reg&3)+8*(reg>>2)+4*(lane>>5).
    // regs 0..7 -> m<16 (vertex 0), regs 8..15 -> m>=16 (vertex 1); lane^32 holds the other 8 d's.
    {
      float m0 = acc0[0], m1 = acc0[8];
#pragma unroll
      for (int k = 1; k < 8; ++k) { m0 = fmaxf(m0, acc0[k]); m1 = fmaxf(m1, acc0[8+k]); }
      m0 = fmaxf(m0, __shfl_xor(m0, 32, 64));
      m1 = fmaxf(m1, __shfl_xor(m1, 32, 64));
      float v = (hi ? m1 : m0) + biasv;
      out[(size_t)(vp0*2 + hi)*64 + fh*32 + (l & 31)] = fmaxf(v, 0.f);
    }
    if (vp1 < NPAIR) {
      float m0 = acc1[0], m1 = acc1[8];
#pragma unroll
      for (int k = 1; k < 8; ++k) { m0 = fmaxf(m0, acc1[k]); m1 = fmaxf(m1, acc1[8+k]); }
      m0 = fmaxf(m0, __shfl_xor(m0, 32, 64));
      m1 = fmaxf(m1, __shfl_xor(m1, 32, 64));
      float v = (hi ? m1 : m0) + biasv;
      out[(size_t)(vp1*2 + hi)*64 + fh*32 + (l & 31)] = fmaxf(v, 0.f);
    }
  }
}

extern "C" void kernel_launch(void* const* d_in, const int* in_sizes, int n_in,
                              void* d_out, int out_size, void* d_ws, size_t ws_size,
                              hipStream_t stream) {
  const float* y     = (const float*)d_in[0];
  const int*   em    = (const int*)  d_in[1];
  const float* kern  = (const float*)d_in[2];
  const float* ckern = (const float*)d_in[3];
  const float* bias  = (const float*)d_in[4];
  float* out = (float*)d_out;
  unsigned short* bpack = (unsigned short*)d_ws;   // 200704 bytes used

  // opt in to >64KB dynamic LDS (idempotent; host-side, graph-capture safe)
  hipFuncSetAttribute(reinterpret_cast<const void*>(conv_kernel),
                      hipFuncAttributeMaxDynamicSharedMemorySize, LDS_TOT);

  prepack_kernel<<<(2*BPACK_HALF_USHORT + 255)/256, 256, 0, stream>>>(kern, ckern, bpack);
  conv_kernel<<<256, 256, LDS_TOT, stream>>>(y, em, bias, bpack, out);
}